// Round 9
// baseline (217.980 us; speedup 1.0000x reference)
//
#include <hip/hip_runtime.h>
#include <hip/hip_bf16.h>

#define LN_EPS 1e-5f
#define SLOPE 0.01f

typedef short bf16x8 __attribute__((ext_vector_type(8)));
typedef float f32x4 __attribute__((ext_vector_type(4)));

// ---------------------------------------------------------------------------
// Kernel 1 (merged prep):
//  blocks 0..1023:  U/V rows (+bf16 copies) + per-row {sum,sumsq} stats
//     bx>>1 = i, bx&1 = isV
//     U[i,d] = robot[i]@W1[0:256] + lang@W1[256:320]
//     V[i,d] = object[i]@W1[320:576] + lang@W1[576:640] + b1
//     stats: [0..511]=sU, [512..1023]=qU, [1024..1535]=sV, [1536..2047]=qV
//  blocks 1024..1123: W2 -> W2F fragment-major bf16:
//     W2F[((kk*20+frag)*512) + l*8 + e] = W2[(kk*32+(l>>4)*8+e)*320 + frag*16 + (l&15)]
// ---------------------------------------------------------------------------
__global__ __launch_bounds__(320) void prep_kernel(
    const float* __restrict__ robot, const float* __restrict__ object,
    const float* __restrict__ lang, const float* __restrict__ W1,
    const float* __restrict__ b1, const float* __restrict__ W2,
    float* __restrict__ U, float* __restrict__ V,
    __hip_bfloat16* __restrict__ Ub, __hip_bfloat16* __restrict__ Vb,
    float* __restrict__ stats, __hip_bfloat16* __restrict__ W2F)
{
  __shared__ float red[5][2];
  __shared__ float tile[32][33];
  const int bx = blockIdx.x;
  const int tid = threadIdx.x;

  if (bx < 1024) {
    const int i = bx >> 1;
    const int isV = bx & 1;
    const int d = tid;
    const float* __restrict__ src   = isV ? object : robot;
    const float* __restrict__ Wbase = W1 + (isV ? 320 * 320 : 0);

    // 4 independent accumulator chains (break the 4-cyc FMA dep latency)
    float a0 = 0.f, a1 = 0.f, a2 = 0.f, a3 = 0.f;
#pragma unroll 4
    for (int k = 0; k < 256; k += 4) {
      a0 = fmaf(src[i * 256 + k + 0], Wbase[(k + 0) * 320 + d], a0);
      a1 = fmaf(src[i * 256 + k + 1], Wbase[(k + 1) * 320 + d], a1);
      a2 = fmaf(src[i * 256 + k + 2], Wbase[(k + 2) * 320 + d], a2);
      a3 = fmaf(src[i * 256 + k + 3], Wbase[(k + 3) * 320 + d], a3);
    }
#pragma unroll 4
    for (int l = 0; l < 64; l += 4) {
      a0 = fmaf(lang[l + 0], Wbase[(256 + l + 0) * 320 + d], a0);
      a1 = fmaf(lang[l + 1], Wbase[(256 + l + 1) * 320 + d], a1);
      a2 = fmaf(lang[l + 2], Wbase[(256 + l + 2) * 320 + d], a2);
      a3 = fmaf(lang[l + 3], Wbase[(256 + l + 3) * 320 + d], a3);
    }
    float acc = (a0 + a1) + (a2 + a3);
    if (isV) acc += b1[d];

    (isV ? V : U)[i * 320 + d] = acc;
    (isV ? Vb : Ub)[i * 320 + d] = __float2bfloat16(acc);

    float s = acc, q = acc * acc;
#pragma unroll
    for (int m = 1; m < 64; m <<= 1) {
      s += __shfl_xor(s, m);
      q += __shfl_xor(q, m);
    }
    const int w = d >> 6, lane = d & 63;
    if (lane == 0) { red[w][0] = s; red[w][1] = q; }
    __syncthreads();
    if (d == 0) {
      float s0 = 0.f, q0 = 0.f;
      for (int t = 0; t < 5; ++t) { s0 += red[t][0]; q0 += red[t][1]; }
      stats[isV * 1024 + i] = s0;
      stats[isV * 1024 + 512 + i] = q0;
    }
  } else {
    const int t = bx - 1024;              // 0..99
    const int d0 = (t % 10) * 32;         // col base (2 frags)
    const int kk = t / 10;                // k-slice
    if (tid < 256) {
      const int tx = tid & 31, ty = tid >> 5;  // ty 0..7
#pragma unroll
      for (int r = 0; r < 32; r += 8)
        tile[ty + r][tx] = W2[((kk * 32) + ty + r) * 320 + d0 + tx];
    }
    __syncthreads();
    if (tid < 256) {
      const int fl   = tid >> 7;        // frag_local 0..1
      const int l    = (tid >> 1) & 63; // lane
      const int half = tid & 1;         // 0..1
      const int frag = (d0 >> 4) + fl;
      __hip_bfloat16* dst = W2F + ((kk * 20 + frag) * 512) + l * 8 + half * 4;
#pragma unroll
      for (int e = 0; e < 4; ++e)
        dst[e] = __float2bfloat16(tile[(l >> 4) * 8 + half * 4 + e]
                                      [fl * 16 + (l & 15)]);
    }
  }
}

// ---------------------------------------------------------------------------
// Kernel 2: fused. 256 thr (4 waves), tile (i, 64 j's).
// Init: stage U/g1/be1 to LDS; compute the 64 LN1 cross-terms dot(U[i],V[jc])
// on the (otherwise idle) MFMA pipe: broadcast-A = Ub[i] (all 16 A-rows
// identical), B = Vb[jc] for the wave's 16 j-cols -> C row 0 = the dots.
// P1: elementwise LN1+leaky -> h1 (XOR-swizzled LDS), stats algebraic.
// GEMM: wave w owns 64 rows x cols [w*80,w*80+80): mf=4, nf=5, acc=80 VGPR.
// B from fragment-major W2F, double-buffered across K-steps.
// ---------------------------------------------------------------------------
__global__ __launch_bounds__(256, 3) void fused_main(
    const float* __restrict__ U, const float* __restrict__ V,
    const __hip_bfloat16* __restrict__ Ub, const __hip_bfloat16* __restrict__ Vb,
    const __hip_bfloat16* __restrict__ W2F, const float* __restrict__ stats,
    const float* __restrict__ g1, const float* __restrict__ be1,
    const float* __restrict__ b2, const float* __restrict__ g2,
    const float* __restrict__ be2, const float* __restrict__ W3,
    const float* __restrict__ b3, float* __restrict__ out)
{
  __shared__ __align__(16) __hip_bfloat16 h1[64 * 320];   // 40 KB
  __shared__ __align__(16) float U_lds[320], g1_lds[320], be1_lds[320];
  __shared__ float dt_lds[64];
  __shared__ float part[64][4][2];
  __shared__ float pdot[64][4];

  const int i   = blockIdx.x;
  const int j0  = blockIdx.y * 64;
  const int tid = threadIdx.x;
  const int lane = tid & 63;
  const int w    = tid >> 6;
  const int r16  = lane & 15;
  const int g    = lane >> 4;
  const int row  = tid >> 2;   // 0..63  (4 threads per row)
  const int seg  = tid & 3;    // 80-elem segment

  // ---- init: stage U row, g1, be1
  for (int t = tid; t < 320; t += 256) {
    U_lds[t]   = U[i * 320 + t];
    g1_lds[t]  = g1[t];
    be1_lds[t] = be1[t];
  }

  // ---- MFMA dot: wave w covers j-cols j0 + w*16 + r16
  {
    const __hip_bfloat16* __restrict__ Ubrow = Ub + i * 320 + g * 8;
    const __hip_bfloat16* __restrict__ Vbrow =
        Vb + (size_t)(j0 + w * 16 + r16) * 320 + g * 8;
    f32x4 accd = (f32x4){0.f, 0.f, 0.f, 0.f};
#pragma unroll
    for (int kk = 0; kk < 10; ++kk) {
      const bf16x8 da = *(const bf16x8*)(Ubrow + kk * 32);
      const bf16x8 db = *(const bf16x8*)(Vbrow + kk * 32);
      accd = __builtin_amdgcn_mfma_f32_16x16x32_bf16(da, db, accd, 0, 0, 0);
    }
    if (lane < 16)                      // C row 0: lanes 0..15, reg 0
      dt_lds[w * 16 + lane] = accd[0];
  }

  // ---- prologue loads for P1 / GEMM (issued before the barrier)
  const float* __restrict__ Vrow = V + (j0 + row) * 320 + seg * 80;
  f32x4 vreg[20];
#pragma unroll
  for (int m = 0; m < 20; ++m)
    vreg[m] = *(const f32x4*)(Vrow + m * 4);
  const float sVr = stats[1024 + j0 + row];
  const float qVr = stats[1536 + j0 + row];
  const float sU  = stats[i], qU = stats[512 + i];

  const int wc = w;
  const __hip_bfloat16* __restrict__ Bf = W2F + (size_t)(wc * 5) * 512 + lane * 8;
  bf16x8 bbuf[2][5];
#pragma unroll
  for (int nf = 0; nf < 5; ++nf)
    bbuf[0][nf] = *(const bf16x8*)(Bf + nf * 512);

  __syncthreads();

  // ---- P1: LN1 stats from algebra, elementwise LN1 + leaky -> h1
  const float dt   = dt_lds[row];
  const float mu   = (sU + sVr) * (1.f / 320.f);
  const float var  = (qU + 2.f * dt + qVr) * (1.f / 320.f) - mu * mu;
  const float rs   = rsqrtf(var + LN_EPS);
  const float murs = mu * rs;
  {
    const unsigned swz  = (unsigned)((row & 7) << 4);
    const unsigned base = (unsigned)row * 640u + (unsigned)seg * 160u;
#pragma unroll
    for (int m = 0; m < 10; ++m) {
      const int d = seg * 80 + m * 8;
      const f32x4 va = vreg[2 * m];
      const f32x4 vb = vreg[2 * m + 1];
      const f32x4 ua = *(const f32x4*)&U_lds[d];
      const f32x4 ub = *(const f32x4*)&U_lds[d + 4];
      const f32x4 ga = *(const f32x4*)&g1_lds[d];
      const f32x4 gb = *(const f32x4*)&g1_lds[d + 4];
      const f32x4 ea = *(const f32x4*)&be1_lds[d];
      const f32x4 eb = *(const f32x4*)&be1_lds[d + 4];
      union { bf16x8 v; __hip_bfloat16 e[8]; } pk;
#pragma unroll
      for (int e = 0; e < 4; ++e) {
        const float x = ua[e] + va[e];
        float hv = fmaf(fmaf(x, rs, -murs), ga[e], ea[e]);
        hv = fmaxf(hv, SLOPE * hv);
        pk.e[e] = __float2bfloat16(hv);
      }
#pragma unroll
      for (int e = 0; e < 4; ++e) {
        const float x = ub[e] + vb[e];
        float hv = fmaf(fmaf(x, rs, -murs), gb[e], eb[e]);
        hv = fmaxf(hv, SLOPE * hv);
        pk.e[4 + e] = __float2bfloat16(hv);
      }
      *(bf16x8*)((char*)h1 + ((base + (unsigned)m * 16u) ^ swz)) = pk.v;
    }
  }
  __syncthreads();

  // ---- P2: GEMM. wave w: rows 0..63 (mf=4), cols w*80..+80 (nf=5).
  f32x4 acc[4][5];
#pragma unroll
  for (int mf = 0; mf < 4; ++mf)
#pragma unroll
    for (int nf = 0; nf < 5; ++nf)
      acc[mf][nf] = (f32x4){0.f, 0.f, 0.f, 0.f};

  const unsigned swzA = (unsigned)((r16 & 7) << 4);
  unsigned arow[4];
#pragma unroll
  for (int mf = 0; mf < 4; ++mf)
    arow[mf] = (unsigned)(mf * 16 + r16) * 640u;

#pragma unroll
  for (int kk = 0; kk < 10; ++kk) {
    const int cur = kk & 1, nxt = cur ^ 1;
    if (kk < 9) {
#pragma unroll
      for (int nf = 0; nf < 5; ++nf)
        bbuf[nxt][nf] = *(const bf16x8*)(Bf + ((kk + 1) * 20 + nf) * 512);
    }
    const unsigned k2 = (unsigned)((kk * 32 + g * 8) * 2);
    bf16x8 a[4];
#pragma unroll
    for (int mf = 0; mf < 4; ++mf)
      a[mf] = *(const bf16x8*)((const char*)h1 + ((arow[mf] + k2) ^ swzA));
#pragma unroll
    for (int nf = 0; nf < 5; ++nf)
#pragma unroll
      for (int mf = 0; mf < 4; ++mf)
        acc[mf][nf] = __builtin_amdgcn_mfma_f32_16x16x32_bf16(
            a[mf], bbuf[cur][nf], acc[mf][nf], 0, 0, 0);
  }

  // ---- epilogue params (global, L2-hot)
  float b2c[5], g2c[5], be2c[5], w3c[5];
#pragma unroll
  for (int nf = 0; nf < 5; ++nf) {
    const int col = wc * 80 + nf * 16 + r16;
    b2c[nf]  = b2[col];
    g2c[nf]  = g2[col];
    be2c[nf] = be2[col];
    w3c[nf]  = W3[col];
  }
#pragma unroll
  for (int nf = 0; nf < 5; ++nf)
#pragma unroll
    for (int mf = 0; mf < 4; ++mf)
#pragma unroll
      for (int r = 0; r < 4; ++r)
        acc[mf][nf][r] += b2c[nf];

  // ---- LN2 stats. global row = mf*16 + g*4 + r
#pragma unroll
  for (int mf = 0; mf < 4; ++mf) {
#pragma unroll
    for (int r = 0; r < 4; ++r) {
      float s = 0.f, q = 0.f;
#pragma unroll
      for (int nf = 0; nf < 5; ++nf) {
        const float v = acc[mf][nf][r];
        s += v;
        q = fmaf(v, v, q);
      }
#pragma unroll
      for (int m = 1; m < 16; m <<= 1) {
        s += __shfl_xor(s, m);
        q += __shfl_xor(q, m);
      }
      if (r16 == 0) {
        const int rw = mf * 16 + g * 4 + r;
        part[rw][wc][0] = s;
        part[rw][wc][1] = q;
      }
    }
  }
  __syncthreads();

  // ---- LN2 apply + leaky + dot W3
#pragma unroll
  for (int mf = 0; mf < 4; ++mf) {
#pragma unroll
    for (int r = 0; r < 4; ++r) {
      const int rw = mf * 16 + g * 4 + r;
      const float s = part[rw][0][0] + part[rw][1][0] +
                      part[rw][2][0] + part[rw][3][0];
      const float q = part[rw][0][1] + part[rw][1][1] +
                      part[rw][2][1] + part[rw][3][1];
      const float mu2  = s * (1.f / 320.f);
      const float var2 = q * (1.f / 320.f) - mu2 * mu2;
      const float rs2  = rsqrtf(var2 + LN_EPS);
      const float murs2 = mu2 * rs2;
      float dsum = 0.f;
#pragma unroll
      for (int nf = 0; nf < 5; ++nf) {
        float v = fmaf(fmaf(acc[mf][nf][r], rs2, -murs2), g2c[nf], be2c[nf]);
        v = fmaxf(v, SLOPE * v);
        dsum = fmaf(v, w3c[nf], dsum);
      }
#pragma unroll
      for (int m = 1; m < 16; m <<= 1)
        dsum += __shfl_xor(dsum, m);
      if (r16 == 0)
        pdot[rw][wc] = dsum;
    }
  }
  __syncthreads();

  if (tid < 64) {
    const float tot = pdot[tid][0] + pdot[tid][1] + pdot[tid][2] +
                      pdot[tid][3] + b3[0];
    out[i * 512 + j0 + tid] = fabsf(tot);
  }
}

// ---------------------------------------------------------------------------
extern "C" void kernel_launch(void* const* d_in, const int* in_sizes, int n_in,
                              void* d_out, int out_size, void* d_ws, size_t ws_size,
                              hipStream_t stream) {
  const float* robot  = (const float*)d_in[0];
  const float* object = (const float*)d_in[1];
  const float* lang   = (const float*)d_in[2];
  const float* W1  = (const float*)d_in[3];
  const float* b1  = (const float*)d_in[4];
  const float* g1  = (const float*)d_in[5];
  const float* be1 = (const float*)d_in[6];
  const float* W2  = (const float*)d_in[7];
  const float* b2  = (const float*)d_in[8];
  const float* g2  = (const float*)d_in[9];
  const float* be2 = (const float*)d_in[10];
  const float* W3  = (const float*)d_in[11];
  const float* b3  = (const float*)d_in[12];
  float* out = (float*)d_out;

  float* U     = (float*)d_ws;            // 512*320
  float* V     = U + 512 * 320;           // 512*320
  float* stats = V + 512 * 320;           // 2048
  __hip_bfloat16* W2F = (__hip_bfloat16*)(stats + 2048);  // 320*320 (frag-major)
  __hip_bfloat16* Ub  = W2F + 320 * 320;  // 512*320
  __hip_bfloat16* Vb  = Ub + 512 * 320;   // 512*320

  prep_kernel<<<1124, 320, 0, stream>>>(robot, object, lang, W1, b1, W2,
                                        U, V, Ub, Vb, stats, W2F);
  fused_main<<<dim3(512, 8), 256, 0, stream>>>(U, V, Ub, Vb, W2F, stats,
                                               g1, be1, b2, g2, be2, W3, b3,
                                               out);
}

// Round 10
// 193.246 us; speedup vs baseline: 1.1280x; 1.1280x over previous
//
#include <hip/hip_runtime.h>
#include <hip/hip_bf16.h>

#define LN_EPS 1e-5f
#define SLOPE 0.01f

typedef short bf16x8 __attribute__((ext_vector_type(8)));
typedef float f32x4 __attribute__((ext_vector_type(4)));

// ---------------------------------------------------------------------------
// Kernel 1 (merged prep):
//  blocks 0..255: U/V, 4 rows per block (W1 reuse across rows: L2 traffic /4)
//     i0=(bx>>1)*4, isV=bx&1
//     U[i,d] = robot[i]@W1[0:256] + lang@W1[256:320]
//     V[i,d] = object[i]@W1[320:576] + lang@W1[576:640] + b1
//     also Ub (linear bf16) / VbF (dot-fragment-major bf16), row stats
//     stats: [0..511]=sU, [512..1023]=qU, [1024..1535]=sV, [1536..2047]=qV
//  blocks 256..355: W2 -> W2F fragment-major bf16 (GEMM B operand)
// ---------------------------------------------------------------------------
__global__ __launch_bounds__(320) void prep_kernel(
    const float* __restrict__ robot, const float* __restrict__ object,
    const float* __restrict__ lang, const float* __restrict__ W1,
    const float* __restrict__ b1, const float* __restrict__ W2,
    float* __restrict__ U, float* __restrict__ V,
    __hip_bfloat16* __restrict__ Ub, __hip_bfloat16* __restrict__ VbF,
    float* __restrict__ stats, __hip_bfloat16* __restrict__ W2F)
{
  __shared__ float sh[4][321];
  __shared__ float tile[32][33];
  const int bx = blockIdx.x;
  const int tid = threadIdx.x;

  if (bx < 256) {
    const int i0  = (bx >> 1) * 4;
    const int isV = bx & 1;
    const int d   = tid;
    const float* __restrict__ src   = isV ? object : robot;
    const float* __restrict__ Wbase = W1 + (isV ? 320 * 320 : 0);

    float a0 = 0.f, a1 = 0.f, a2 = 0.f, a3 = 0.f;
#pragma unroll 4
    for (int k = 0; k < 256; ++k) {
      const float w1v = Wbase[k * 320 + d];
      a0 = fmaf(src[(i0 + 0) * 256 + k], w1v, a0);
      a1 = fmaf(src[(i0 + 1) * 256 + k], w1v, a1);
      a2 = fmaf(src[(i0 + 2) * 256 + k], w1v, a2);
      a3 = fmaf(src[(i0 + 3) * 256 + k], w1v, a3);
    }
    float la = 0.f;
#pragma unroll 4
    for (int l = 0; l < 64; ++l)
      la = fmaf(lang[l], Wbase[(256 + l) * 320 + d], la);
    if (isV) la += b1[d];
    a0 += la; a1 += la; a2 += la; a3 += la;

    const float av[4] = {a0, a1, a2, a3};
#pragma unroll
    for (int r = 0; r < 4; ++r) {
      const int i = i0 + r;
      (isV ? V : U)[i * 320 + d] = av[r];
      if (!isV) {
        Ub[i * 320 + d] = __float2bfloat16(av[r]);
      } else {
        const int jt = i >> 4, kkv = d >> 5, gv = (d >> 3) & 3, ev = d & 7;
        VbF[((jt * 10 + kkv) * 512) + (gv * 16 + (i & 15)) * 8 + ev] =
            __float2bfloat16(av[r]);
      }
      sh[r][d] = av[r];
    }
    __syncthreads();
    const int w = tid >> 6, lane = tid & 63;
    if (w < 4) {
      float s = 0.f, q = 0.f;
#pragma unroll
      for (int c = 0; c < 5; ++c) {
        const float v = sh[w][lane + c * 64];
        s += v;
        q = fmaf(v, v, q);
      }
#pragma unroll
      for (int m = 1; m < 64; m <<= 1) {
        s += __shfl_xor(s, m);
        q += __shfl_xor(q, m);
      }
      if (lane == 0) {
        stats[isV * 1024 + i0 + w] = s;
        stats[isV * 1024 + 512 + i0 + w] = q;
      }
    }
  } else {
    const int t = bx - 256;               // 0..99
    const int d0 = (t % 10) * 32;         // col base (2 frags)
    const int kk = t / 10;                // k-slice
    if (tid < 256) {
      const int tx = tid & 31, ty = tid >> 5;  // ty 0..7
#pragma unroll
      for (int r = 0; r < 32; r += 8)
        tile[ty + r][tx] = W2[((kk * 32) + ty + r) * 320 + d0 + tx];
    }
    __syncthreads();
    if (tid < 256) {
      const int fl   = tid >> 7;        // frag_local 0..1
      const int l    = (tid >> 1) & 63; // lane
      const int half = tid & 1;         // 0..1
      const int frag = (d0 >> 4) + fl;
      __hip_bfloat16* dst = W2F + ((kk * 20 + frag) * 512) + l * 8 + half * 4;
#pragma unroll
      for (int e = 0; e < 4; ++e)
        dst[e] = __float2bfloat16(tile[(l >> 4) * 8 + half * 4 + e]
                                      [fl * 16 + (l & 15)]);
    }
  }
}

// ---------------------------------------------------------------------------
// Kernel 2: fused. 256 thr (4 waves), tile (i, 64 j's).
// Init: stage U/g1/be1 to LDS; LN1 cross-terms dot(U[i],V[jc]) on the idle
// MFMA pipe (broadcast-A = Ub[i]; B from fragment-major VbF -> coalesced).
// P1: elementwise LN1+leaky -> h1 (XOR-swizzled LDS), stats algebraic.
// GEMM: wave w owns 64 rows x cols [w*80,w*80+80): mf=4, nf=5.
// B from fragment-major W2F, double-buffered across K-steps.
// Epilogue: LN2 + leaky + W3-dot via LDS partial sums (no shuffle chains);
// f32 scratch aliases the (dead) h1 buffer.
// ---------------------------------------------------------------------------
__global__ __launch_bounds__(256, 3) void fused_main(
    const float* __restrict__ U, const float* __restrict__ V,
    const __hip_bfloat16* __restrict__ Ub, const __hip_bfloat16* __restrict__ VbF,
    const __hip_bfloat16* __restrict__ W2F, const float* __restrict__ stats,
    const float* __restrict__ g1, const float* __restrict__ be1,
    const float* __restrict__ b2, const float* __restrict__ g2,
    const float* __restrict__ be2, const float* __restrict__ W3,
    const float* __restrict__ b3, float* __restrict__ out)
{
  __shared__ __align__(16) __hip_bfloat16 h1[64 * 320];   // 40 KB (GEMM A / epilogue scratch)
  __shared__ __align__(16) float U_lds[320], g1_lds[320], be1_lds[320];
  __shared__ float dt_lds[64];
  __shared__ float s4[64][5], q4[64][5], e4[64][5];
  __shared__ float rsm[64][2];

  const int i   = blockIdx.x;
  const int j0  = blockIdx.y * 64;
  const int tid = threadIdx.x;
  const int lane = tid & 63;
  const int w    = tid >> 6;
  const int r16  = lane & 15;
  const int g    = lane >> 4;
  const int row  = tid >> 2;   // 0..63  (4 threads per row)
  const int seg  = tid & 3;    // 80-elem segment

  // ---- init: stage U row, g1, be1
  for (int t = tid; t < 320; t += 256) {
    U_lds[t]   = U[i * 320 + t];
    g1_lds[t]  = g1[t];
    be1_lds[t] = be1[t];
  }

  // ---- MFMA dot: wave w covers j-cols j0 + w*16 + r16. B from VbF (coalesced).
  {
    const __hip_bfloat16* __restrict__ Ubrow = Ub + i * 320 + g * 8;
    const __hip_bfloat16* __restrict__ VbFp =
        VbF + ((size_t)((j0 >> 4) + w) * 10) * 512 + lane * 8;
    f32x4 accd = (f32x4){0.f, 0.f, 0.f, 0.f};
#pragma unroll
    for (int kk = 0; kk < 10; ++kk) {
      const bf16x8 da = *(const bf16x8*)(Ubrow + kk * 32);
      const bf16x8 db = *(const bf16x8*)(VbFp + kk * 512);
      accd = __builtin_amdgcn_mfma_f32_16x16x32_bf16(da, db, accd, 0, 0, 0);
    }
    if (lane < 16)                      // C row 0: lanes 0..15, reg 0
      dt_lds[w * 16 + lane] = accd[0];
  }

  // ---- prologue loads for P1 / GEMM (issued before the barrier)
  const float* __restrict__ Vrow = V + (j0 + row) * 320 + seg * 80;
  f32x4 vreg[20];
#pragma unroll
  for (int m = 0; m < 20; ++m)
    vreg[m] = *(const f32x4*)(Vrow + m * 4);
  const float sVr = stats[1024 + j0 + row];
  const float qVr = stats[1536 + j0 + row];
  const float sU  = stats[i], qU = stats[512 + i];

  const int wc = w;
  const __hip_bfloat16* __restrict__ Bf = W2F + (size_t)(wc * 5) * 512 + lane * 8;
  bf16x8 bbuf[2][5];
#pragma unroll
  for (int nf = 0; nf < 5; ++nf)
    bbuf[0][nf] = *(const bf16x8*)(Bf + nf * 512);

  __syncthreads();

  // ---- P1: LN1 stats from algebra, elementwise LN1 + leaky -> h1
  const float dt   = dt_lds[row];
  const float mu   = (sU + sVr) * (1.f / 320.f);
  const float var  = (qU + 2.f * dt + qVr) * (1.f / 320.f) - mu * mu;
  const float rs   = rsqrtf(var + LN_EPS);
  const float murs = mu * rs;
  {
    const unsigned swz  = (unsigned)((row & 7) << 4);
    const unsigned base = (unsigned)row * 640u + (unsigned)seg * 160u;
#pragma unroll
    for (int m = 0; m < 10; ++m) {
      const int d = seg * 80 + m * 8;
      const f32x4 va = vreg[2 * m];
      const f32x4 vb = vreg[2 * m + 1];
      const f32x4 ua = *(const f32x4*)&U_lds[d];
      const f32x4 ub = *(const f32x4*)&U_lds[d + 4];
      const f32x4 ga = *(const f32x4*)&g1_lds[d];
      const f32x4 gb = *(const f32x4*)&g1_lds[d + 4];
      const f32x4 ea = *(const f32x4*)&be1_lds[d];
      const f32x4 eb = *(const f32x4*)&be1_lds[d + 4];
      union { bf16x8 v; __hip_bfloat16 e[8]; } pk;
#pragma unroll
      for (int e = 0; e < 4; ++e) {
        const float x = ua[e] + va[e];
        float hv = fmaf(fmaf(x, rs, -murs), ga[e], ea[e]);
        hv = fmaxf(hv, SLOPE * hv);
        pk.e[e] = __float2bfloat16(hv);
      }
#pragma unroll
      for (int e = 0; e < 4; ++e) {
        const float x = ub[e] + vb[e];
        float hv = fmaf(fmaf(x, rs, -murs), gb[e], eb[e]);
        hv = fmaxf(hv, SLOPE * hv);
        pk.e[4 + e] = __float2bfloat16(hv);
      }
      *(bf16x8*)((char*)h1 + ((base + (unsigned)m * 16u) ^ swz)) = pk.v;
    }
  }
  __syncthreads();

  // ---- P2: GEMM. wave w: rows 0..63 (mf=4), cols w*80..+80 (nf=5).
  f32x4 acc[4][5];
#pragma unroll
  for (int mf = 0; mf < 4; ++mf)
#pragma unroll
    for (int nf = 0; nf < 5; ++nf)
      acc[mf][nf] = (f32x4){0.f, 0.f, 0.f, 0.f};

  const unsigned swzA = (unsigned)((r16 & 7) << 4);
  unsigned arow[4];
#pragma unroll
  for (int mf = 0; mf < 4; ++mf)
    arow[mf] = (unsigned)(mf * 16 + r16) * 640u;

#pragma unroll
  for (int kk = 0; kk < 10; ++kk) {
    const int cur = kk & 1, nxt = cur ^ 1;
    if (kk < 9) {
#pragma unroll
      for (int nf = 0; nf < 5; ++nf)
        bbuf[nxt][nf] = *(const bf16x8*)(Bf + ((kk + 1) * 20 + nf) * 512);
    }
    const unsigned k2 = (unsigned)((kk * 32 + g * 8) * 2);
    bf16x8 a[4];
#pragma unroll
    for (int mf = 0; mf < 4; ++mf)
      a[mf] = *(const bf16x8*)((const char*)h1 + ((arow[mf] + k2) ^ swzA));
#pragma unroll
    for (int nf = 0; nf < 5; ++nf)
#pragma unroll
      for (int mf = 0; mf < 4; ++mf)
        acc[mf][nf] = __builtin_amdgcn_mfma_f32_16x16x32_bf16(
            a[mf], bbuf[cur][nf], acc[mf][nf], 0, 0, 0);
  }

  // ---- epilogue params (global, L2-hot); h2_pre = acc + b2
  float b2c[5], g2c[5], be2c[5], w3c[5];
#pragma unroll
  for (int nf = 0; nf < 5; ++nf) {
    const int col = wc * 80 + nf * 16 + r16;
    b2c[nf]  = b2[col];
    g2c[nf]  = g2[col];
    be2c[nf] = be2[col];
    w3c[nf]  = W3[col];
  }
#pragma unroll
  for (int nf = 0; nf < 5; ++nf)
#pragma unroll
    for (int mf = 0; mf < 4; ++mf)
#pragma unroll
      for (int r = 0; r < 4; ++r)
        acc[mf][nf][r] += b2c[nf];

  // ---- LN2 via LDS partial sums. scr aliases dead h1 (10240 f32).
  float* scr = (float*)h1;   // [0..4159]=s partials [64][65]; [4160..8319]=q
  __syncthreads();           // all GEMM h1 reads complete

  // A: per-lane partials over this lane's 5 cols, per (mf,r)
#pragma unroll
  for (int mf = 0; mf < 4; ++mf) {
#pragma unroll
    for (int r = 0; r < 4; ++r) {
      float s = 0.f, q = 0.f;
#pragma unroll
      for (int nf = 0; nf < 5; ++nf) {
        const float v = acc[mf][nf][r];
        s += v;
        q = fmaf(v, v, q);
      }
      const int rw = mf * 16 + g * 4 + r;
      scr[rw * 65 + wc * 16 + r16] = s;
      scr[4160 + rw * 65 + wc * 16 + r16] = q;
    }
  }
  __syncthreads();

  // B: 256 threads: row=tid&63, quarter qq=tid>>6 sums 16 partials
  {
    const int r = tid & 63, qq = tid >> 6;
    float s = 0.f, q = 0.f;
#pragma unroll
    for (int k = 0; k < 16; ++k) {
      s += scr[r * 65 + qq * 16 + k];
      q += scr[4160 + r * 65 + qq * 16 + k];
    }
    s4[r][qq] = s;
    q4[r][qq] = q;
  }
  __syncthreads();

  // C: row stats
  if (tid < 64) {
    const float s = s4[tid][0] + s4[tid][1] + s4[tid][2] + s4[tid][3];
    const float q = q4[tid][0] + q4[tid][1] + q4[tid][2] + q4[tid][3];
    const float mu2  = s * (1.f / 320.f);
    const float var2 = q * (1.f / 320.f) - mu2 * mu2;
    const float rs2  = rsqrtf(var2 + LN_EPS);
    rsm[tid][0] = rs2;
    rsm[tid][1] = mu2 * rs2;
  }
  __syncthreads();

  // D: apply LN2 + leaky + per-lane W3-dot partial (overwrites s-partials)
#pragma unroll
  for (int mf = 0; mf < 4; ++mf) {
#pragma unroll
    for (int r = 0; r < 4; ++r) {
      const int rw = mf * 16 + g * 4 + r;
      const float rs2 = rsm[rw][0], murs2 = rsm[rw][1];
      float dsum = 0.f;
#pragma unroll
      for (int nf = 0; nf < 5; ++nf) {
        float v = fmaf(fmaf(acc[mf][nf][r], rs2, -murs2), g2c[nf], be2c[nf]);
        v = fmaxf(v, SLOPE * v);
        dsum = fmaf(v, w3c[nf], dsum);
      }
      scr[rw * 65 + wc * 16 + r16] = dsum;
    }
  }
  __syncthreads();

  // E1: quarter sums
  {
    const int r = tid & 63, qq = tid >> 6;
    float s = 0.f;
#pragma unroll
    for (int k = 0; k < 16; ++k)
      s += scr[r * 65 + qq * 16 + k];
    e4[r][qq] = s;
  }
  __syncthreads();

  // E2: final
  if (tid < 64) {
    const float tot = e4[tid][0] + e4[tid][1] + e4[tid][2] + e4[tid][3] + b3[0];
    out[i * 512 + j0 + tid] = fabsf(tot);
  }
}

// ---------------------------------------------------------------------------
extern "C" void kernel_launch(void* const* d_in, const int* in_sizes, int n_in,
                              void* d_out, int out_size, void* d_ws, size_t ws_size,
                              hipStream_t stream) {
  const float* robot  = (const float*)d_in[0];
  const float* object = (const float*)d_in[1];
  const float* lang   = (const float*)d_in[2];
  const float* W1  = (const float*)d_in[3];
  const float* b1  = (const float*)d_in[4];
  const float* g1  = (const float*)d_in[5];
  const float* be1 = (const float*)d_in[6];
  const float* W2  = (const float*)d_in[7];
  const float* b2  = (const float*)d_in[8];
  const float* g2  = (const float*)d_in[9];
  const float* be2 = (const float*)d_in[10];
  const float* W3  = (const float*)d_in[11];
  const float* b3  = (const float*)d_in[12];
  float* out = (float*)d_out;

  float* U     = (float*)d_ws;            // 512*320 f32
  float* V     = U + 512 * 320;           // 512*320 f32
  float* stats = V + 512 * 320;           // 2048 f32
  __hip_bfloat16* W2F = (__hip_bfloat16*)(stats + 2048);  // 320*320 bf16 (frag-major)
  __hip_bfloat16* Ub  = W2F + 320 * 320;  // 512*320 bf16 (linear)
  __hip_bfloat16* VbF = Ub + 512 * 320;   // 512*320 bf16 (dot-fragment-major)

  prep_kernel<<<356, 320, 0, stream>>>(robot, object, lang, W1, b1, W2,
                                       U, V, Ub, VbF, stats, W2F);
  fused_main<<<dim3(512, 8), 256, 0, stream>>>(U, V, Ub, VbF, W2F, stats,
                                               g1, be1, b2, g2, be2, W3, b3,
                                               out);
}

// Round 11
// 182.309 us; speedup vs baseline: 1.1957x; 1.0600x over previous
//
#include <hip/hip_runtime.h>
#include <hip/hip_bf16.h>

#define LN_EPS 1e-5f
#define SLOPE 0.01f

typedef short bf16x8 __attribute__((ext_vector_type(8)));
typedef float f32x4 __attribute__((ext_vector_type(4)));

// ---------------------------------------------------------------------------
// Kernel 1 (convert): all-bf16 operand prep, 556 blocks x 256 thr
//  blocks 0..199:   W1 [640x320] -> W1Ft (rows 0..319) / W1Fb (rows 320..639),
//                   fragment-major: dst[((kk*20+frag)*512)+l*8+e] =
//                   src[(kk*32+(l>>4)*8+e)*320 + frag*16 + (l&15)]
//  blocks 200..299: W2 -> W2F (same layout)
//  blocks 300..555: AcatU[i] = [bf16(robot[i]) | bf16(lang)],
//                   AcatV[i] = [bf16(object[i]) | bf16(lang)]   (2 rows/block)
// ---------------------------------------------------------------------------
__global__ __launch_bounds__(256) void convert_kernel(
    const float* __restrict__ robot, const float* __restrict__ object,
    const float* __restrict__ lang, const float* __restrict__ W1,
    const float* __restrict__ W2,
    __hip_bfloat16* __restrict__ AcatU, __hip_bfloat16* __restrict__ AcatV,
    __hip_bfloat16* __restrict__ W1Ft, __hip_bfloat16* __restrict__ W1Fb,
    __hip_bfloat16* __restrict__ W2F)
{
  __shared__ float tile[32][33];
  const int bx = blockIdx.x;
  const int tid = threadIdx.x;

  if (bx < 300) {
    int kk, d0;
    const float* srcbase;
    __hip_bfloat16* dstbase;
    if (bx < 200) {
      kk = bx / 10; d0 = (bx % 10) * 32;
      srcbase = W1 + (size_t)(kk * 32) * 320;
      dstbase = (kk < 10) ? W1Ft : W1Fb;
      if (kk >= 10) kk -= 10;
    } else {
      const int t = bx - 200;
      kk = t / 10; d0 = (t % 10) * 32;
      srcbase = W2 + (size_t)(kk * 32) * 320;
      dstbase = W2F;
    }
    const int tx = tid & 31, ty = tid >> 5;  // ty 0..7
#pragma unroll
    for (int r = 0; r < 32; r += 8)
      tile[ty + r][tx] = srcbase[(ty + r) * 320 + d0 + tx];
    __syncthreads();
    const int fl   = tid >> 7;        // frag_local 0..1
    const int l    = (tid >> 1) & 63; // lane
    const int half = tid & 1;
    const int frag = (d0 >> 4) + fl;
    __hip_bfloat16* dst = dstbase + ((kk * 20 + frag) * 512) + l * 8 + half * 4;
#pragma unroll
    for (int e = 0; e < 4; ++e)
      dst[e] = __float2bfloat16(tile[(l >> 4) * 8 + half * 4 + e]
                                    [fl * 16 + (l & 15)]);
  } else {
    const int i0 = (bx - 300) * 2;
#pragma unroll
    for (int rr = 0; rr < 2; ++rr) {
      const int i = i0 + rr;
      AcatU[i * 320 + tid] = __float2bfloat16(robot[i * 256 + tid]);
      AcatV[i * 320 + tid] = __float2bfloat16(object[i * 256 + tid]);
      if (tid < 64) {
        const __hip_bfloat16 lv = __float2bfloat16(lang[tid]);
        AcatU[i * 320 + 256 + tid] = lv;
        AcatV[i * 320 + 256 + tid] = lv;
      }
    }
  }
}

// ---------------------------------------------------------------------------
// Kernel 2 (prep_gemm): U = AcatU @ W1t (+0), V = AcatV @ W1b (+b1).
// Clone of the fused GEMM core: 256 thr / 4 waves, 64-row i-tile, wave w owns
// all 64 rows x cols [w*80,w*80+80); A staged in XOR-swizzled LDS; B from
// fragment-major W1F, double-buffered. Epilogue: U/V f32, Ub linear bf16,
// VbF dot-fragment-major bf16, per-row {sum,sumsq} -> stats.
// grid = (8 i-tiles, 2 uv)
// ---------------------------------------------------------------------------
__global__ __launch_bounds__(256, 3) void prep_gemm(
    const __hip_bfloat16* __restrict__ AcatU,
    const __hip_bfloat16* __restrict__ AcatV,
    const __hip_bfloat16* __restrict__ W1Ft,
    const __hip_bfloat16* __restrict__ W1Fb,
    const float* __restrict__ b1,
    float* __restrict__ U, float* __restrict__ V,
    __hip_bfloat16* __restrict__ Ub, __hip_bfloat16* __restrict__ VbF,
    float* __restrict__ stats)
{
  __shared__ __align__(16) __hip_bfloat16 hA[64 * 320];   // 40 KB (A / scratch)
  __shared__ float s4[64][5], q4[64][5];

  const int it = blockIdx.x, uv = blockIdx.y;
  const int i0 = it * 64;
  const int tid = threadIdx.x;
  const int lane = tid & 63;
  const int w    = tid >> 6;
  const int r16  = lane & 15;
  const int g    = lane >> 4;
  const int row  = tid >> 2;
  const int seg  = tid & 3;

  const __hip_bfloat16* __restrict__ Acat = uv ? AcatV : AcatU;
  const __hip_bfloat16* __restrict__ W1F  = uv ? W1Fb : W1Ft;

  // ---- stage A rows into swizzled LDS
  {
    const __hip_bfloat16* __restrict__ src =
        Acat + (size_t)(i0 + row) * 320 + seg * 80;
    const unsigned swz  = (unsigned)((row & 7) << 4);
    const unsigned base = (unsigned)row * 640u + (unsigned)seg * 160u;
#pragma unroll
    for (int m = 0; m < 10; ++m) {
      const bf16x8 v = *(const bf16x8*)(src + m * 8);
      *(bf16x8*)((char*)hA + ((base + (unsigned)m * 16u) ^ swz)) = v;
    }
  }

  const int wc = w;
  const __hip_bfloat16* __restrict__ Bf = W1F + (size_t)(wc * 5) * 512 + lane * 8;
  bf16x8 bbuf[2][5];
#pragma unroll
  for (int nf = 0; nf < 5; ++nf)
    bbuf[0][nf] = *(const bf16x8*)(Bf + nf * 512);

  __syncthreads();

  // ---- GEMM (identical structure to fused_main P2)
  f32x4 acc[4][5];
#pragma unroll
  for (int mf = 0; mf < 4; ++mf)
#pragma unroll
    for (int nf = 0; nf < 5; ++nf)
      acc[mf][nf] = (f32x4){0.f, 0.f, 0.f, 0.f};

  const unsigned swzA = (unsigned)((r16 & 7) << 4);
  unsigned arow[4];
#pragma unroll
  for (int mf = 0; mf < 4; ++mf)
    arow[mf] = (unsigned)(mf * 16 + r16) * 640u;

#pragma unroll
  for (int kk = 0; kk < 10; ++kk) {
    const int cur = kk & 1, nxt = cur ^ 1;
    if (kk < 9) {
#pragma unroll
      for (int nf = 0; nf < 5; ++nf)
        bbuf[nxt][nf] = *(const bf16x8*)(Bf + ((kk + 1) * 20 + nf) * 512);
    }
    const unsigned k2 = (unsigned)((kk * 32 + g * 8) * 2);
    bf16x8 a[4];
#pragma unroll
    for (int mf = 0; mf < 4; ++mf)
      a[mf] = *(const bf16x8*)((const char*)hA + ((arow[mf] + k2) ^ swzA));
#pragma unroll
    for (int nf = 0; nf < 5; ++nf)
#pragma unroll
      for (int mf = 0; mf < 4; ++mf)
        acc[mf][nf] = __builtin_amdgcn_mfma_f32_16x16x32_bf16(
            a[mf], bbuf[cur][nf], acc[mf][nf], 0, 0, 0);
  }

  // ---- epilogue: b1 (V only), write U/V, Ub/VbF, stat partials
  float b1c[5];
#pragma unroll
  for (int nf = 0; nf < 5; ++nf)
    b1c[nf] = uv ? b1[wc * 80 + nf * 16 + r16] : 0.f;

  float* scr = (float*)hA;
  __syncthreads();           // hA GEMM reads complete

#pragma unroll
  for (int mf = 0; mf < 4; ++mf) {
#pragma unroll
    for (int r = 0; r < 4; ++r) {
      const int j = i0 + mf * 16 + g * 4 + r;
      float s = 0.f, q = 0.f;
#pragma unroll
      for (int nf = 0; nf < 5; ++nf) {
        const float val = acc[mf][nf][r] + b1c[nf];
        const int d = wc * 80 + nf * 16 + r16;
        if (uv == 0) {
          U[j * 320 + d] = val;
          Ub[j * 320 + d] = __float2bfloat16(val);
        } else {
          V[j * 320 + d] = val;
          VbF[((size_t)(j >> 4) * 10 + (d >> 5)) * 512 +
              (((d >> 3) & 3) * 16 + (j & 15)) * 8 + (d & 7)] =
              __float2bfloat16(val);
        }
        s += val;
        q = fmaf(val, val, q);
      }
      const int rw = mf * 16 + g * 4 + r;
      scr[rw * 65 + wc * 16 + r16] = s;
      scr[4160 + rw * 65 + wc * 16 + r16] = q;
    }
  }
  __syncthreads();

  {
    const int r = tid & 63, qq = tid >> 6;
    float s = 0.f, q = 0.f;
#pragma unroll
    for (int k = 0; k < 16; ++k) {
      s += scr[r * 65 + qq * 16 + k];
      q += scr[4160 + r * 65 + qq * 16 + k];
    }
    s4[r][qq] = s;
    q4[r][qq] = q;
  }
  __syncthreads();

  if (tid < 64) {
    const float s = s4[tid][0] + s4[tid][1] + s4[tid][2] + s4[tid][3];
    const float q = q4[tid][0] + q4[tid][1] + q4[tid][2] + q4[tid][3];
    stats[uv * 1024 + i0 + tid] = s;
    stats[uv * 1024 + 512 + i0 + tid] = q;
  }
}

// ---------------------------------------------------------------------------
// Kernel 3: fused — UNCHANGED from round 10 (98 us, proven).
// ---------------------------------------------------------------------------
__global__ __launch_bounds__(256, 3) void fused_main(
    const float* __restrict__ U, const float* __restrict__ V,
    const __hip_bfloat16* __restrict__ Ub, const __hip_bfloat16* __restrict__ VbF,
    const __hip_bfloat16* __restrict__ W2F, const float* __restrict__ stats,
    const float* __restrict__ g1, const float* __restrict__ be1,
    const float* __restrict__ b2, const float* __restrict__ g2,
    const float* __restrict__ be2, const float* __restrict__ W3,
    const float* __restrict__ b3, float* __restrict__ out)
{
  __shared__ __align__(16) __hip_bfloat16 h1[64 * 320];   // 40 KB (GEMM A / epilogue scratch)
  __shared__ __align__(16) float U_lds[320], g1_lds[320], be1_lds[320];
  __shared__ float dt_lds[64];
  __shared__ float s4[64][5], q4[64][5], e4[64][5];
  __shared__ float rsm[64][2];

  const int i   = blockIdx.x;
  const int j0  = blockIdx.y * 64;
  const int tid = threadIdx.x;
  const int lane = tid & 63;
  const int w    = tid >> 6;
  const int r16  = lane & 15;
  const int g    = lane >> 4;
  const int row  = tid >> 2;   // 0..63  (4 threads per row)
  const int seg  = tid & 3;    // 80-elem segment

  // ---- init: stage U row, g1, be1
  for (int t = tid; t < 320; t += 256) {
    U_lds[t]   = U[i * 320 + t];
    g1_lds[t]  = g1[t];
    be1_lds[t] = be1[t];
  }

  // ---- MFMA dot: wave w covers j-cols j0 + w*16 + r16. B from VbF (coalesced).
  {
    const __hip_bfloat16* __restrict__ Ubrow = Ub + i * 320 + g * 8;
    const __hip_bfloat16* __restrict__ VbFp =
        VbF + ((size_t)((j0 >> 4) + w) * 10) * 512 + lane * 8;
    f32x4 accd = (f32x4){0.f, 0.f, 0.f, 0.f};
#pragma unroll
    for (int kk = 0; kk < 10; ++kk) {
      const bf16x8 da = *(const bf16x8*)(Ubrow + kk * 32);
      const bf16x8 db = *(const bf16x8*)(VbFp + kk * 512);
      accd = __builtin_amdgcn_mfma_f32_16x16x32_bf16(da, db, accd, 0, 0, 0);
    }
    if (lane < 16)                      // C row 0: lanes 0..15, reg 0
      dt_lds[w * 16 + lane] = accd[0];
  }

  // ---- prologue loads for P1 / GEMM (issued before the barrier)
  const float* __restrict__ Vrow = V + (j0 + row) * 320 + seg * 80;
  f32x4 vreg[20];
#pragma unroll
  for (int m = 0; m < 20; ++m)
    vreg[m] = *(const f32x4*)(Vrow + m * 4);
  const float sVr = stats[1024 + j0 + row];
  const float qVr = stats[1536 + j0 + row];
  const float sU  = stats[i], qU = stats[512 + i];

  const int wc = w;
  const __hip_bfloat16* __restrict__ Bf = W2F + (size_t)(wc * 5) * 512 + lane * 8;
  bf16x8 bbuf[2][5];
#pragma unroll
  for (int nf = 0; nf < 5; ++nf)
    bbuf[0][nf] = *(const bf16x8*)(Bf + nf * 512);

  __syncthreads();

  // ---- P1: LN1 stats from algebra, elementwise LN1 + leaky -> h1
  const float dt   = dt_lds[row];
  const float mu   = (sU + sVr) * (1.f / 320.f);
  const float var  = (qU + 2.f * dt + qVr) * (1.f / 320.f) - mu * mu;
  const float rs   = rsqrtf(var + LN_EPS);
  const float murs = mu * rs;
  {
    const unsigned swz  = (unsigned)((row & 7) << 4);
    const unsigned base = (unsigned)row * 640u + (unsigned)seg * 160u;
#pragma unroll
    for (int m = 0; m < 10; ++m) {
      const int d = seg * 80 + m * 8;
      const f32x4 va = vreg[2 * m];
      const f32x4 vb = vreg[2 * m + 1];
      const f32x4 ua = *(const f32x4*)&U_lds[d];
      const f32x4 ub = *(const f32x4*)&U_lds[d + 4];
      const f32x4 ga = *(const f32x4*)&g1_lds[d];
      const f32x4 gb = *(const f32x4*)&g1_lds[d + 4];
      const f32x4 ea = *(const f32x4*)&be1_lds[d];
      const f32x4 eb = *(const f32x4*)&be1_lds[d + 4];
      union { bf16x8 v; __hip_bfloat16 e[8]; } pk;
#pragma unroll
      for (int e = 0; e < 4; ++e) {
        const float x = ua[e] + va[e];
        float hv = fmaf(fmaf(x, rs, -murs), ga[e], ea[e]);
        hv = fmaxf(hv, SLOPE * hv);
        pk.e[e] = __float2bfloat16(hv);
      }
#pragma unroll
      for (int e = 0; e < 4; ++e) {
        const float x = ub[e] + vb[e];
        float hv = fmaf(fmaf(x, rs, -murs), gb[e], eb[e]);
        hv = fmaxf(hv, SLOPE * hv);
        pk.e[4 + e] = __float2bfloat16(hv);
      }
      *(bf16x8*)((char*)h1 + ((base + (unsigned)m * 16u) ^ swz)) = pk.v;
    }
  }
  __syncthreads();

  // ---- P2: GEMM. wave w: rows 0..63 (mf=4), cols w*80..+80 (nf=5).
  f32x4 acc[4][5];
#pragma unroll
  for (int mf = 0; mf < 4; ++mf)
#pragma unroll
    for (int nf = 0; nf < 5; ++nf)
      acc[mf][nf] = (f32x4){0.f, 0.f, 0.f, 0.f};

  const unsigned swzA = (unsigned)((r16 & 7) << 4);
  unsigned arow[4];
#pragma unroll
  for (int mf = 0; mf < 4; ++mf)
    arow[mf] = (unsigned)(mf * 16 + r16) * 640u;

#pragma unroll
  for (int kk = 0; kk < 10; ++kk) {
    const int cur = kk & 1, nxt = cur ^ 1;
    if (kk < 9) {
#pragma unroll
      for (int nf = 0; nf < 5; ++nf)
        bbuf[nxt][nf] = *(const bf16x8*)(Bf + ((kk + 1) * 20 + nf) * 512);
    }
    const unsigned k2 = (unsigned)((kk * 32 + g * 8) * 2);
    bf16x8 a[4];
#pragma unroll
    for (int mf = 0; mf < 4; ++mf)
      a[mf] = *(const bf16x8*)((const char*)h1 + ((arow[mf] + k2) ^ swzA));
#pragma unroll
    for (int nf = 0; nf < 5; ++nf)
#pragma unroll
      for (int mf = 0; mf < 4; ++mf)
        acc[mf][nf] = __builtin_amdgcn_mfma_f32_16x16x32_bf16(
            a[mf], bbuf[cur][nf], acc[mf][nf], 0, 0, 0);
  }

  // ---- epilogue params (global, L2-hot); h2_pre = acc + b2
  float b2c[5], g2c[5], be2c[5], w3c[5];
#pragma unroll
  for (int nf = 0; nf < 5; ++nf) {
    const int col = wc * 80 + nf * 16 + r16;
    b2c[nf]  = b2[col];
    g2c[nf]  = g2[col];
    be2c[nf] = be2[col];
    w3c[nf]  = W3[col];
  }
#pragma unroll
  for (int nf = 0; nf < 5; ++nf)
#pragma unroll
    for (int mf = 0; mf < 4; ++mf)
#pragma unroll
      for (int r = 0; r < 4; ++r)
        acc[mf][nf][r] += b2c[nf];

  // ---- LN2 via LDS partial sums. scr aliases dead h1 (10240 f32).
  float* scr = (float*)h1;   // [0..4159]=s partials [64][65]; [4160..8319]=q
  __syncthreads();           // all GEMM h1 reads complete

  // A: per-lane partials over this lane's 5 cols, per (mf,r)
#pragma unroll
  for (int mf = 0; mf < 4; ++mf) {
#pragma unroll
    for (int r = 0; r < 4; ++r) {
      float s = 0.f, q = 0.f;
#pragma unroll
      for (int nf = 0; nf < 5; ++nf) {
        const float v = acc[mf][nf][r];
        s += v;
        q = fmaf(v, v, q);
      }
      const int rw = mf * 16 + g * 4 + r;
      scr[rw * 65 + wc * 16 + r16] = s;
      scr[4160 + rw * 65 + wc * 16 + r16] = q;
    }
  }
  __syncthreads();

  // B: 256 threads: row=tid&63, quarter qq=tid>>6 sums 16 partials
  {
    const int r = tid & 63, qq = tid >> 6;
    float s = 0.f, q = 0.f;
#pragma unroll
    for (int k = 0; k < 16; ++k) {
      s += scr[r * 65 + qq * 16 + k];
      q += scr[4160 + r * 65 + qq * 16 + k];
    }
    s4[r][qq] = s;
    q4[r][qq] = q;
  }
  __syncthreads();

  // C: row stats
  if (tid < 64) {
    const float s = s4[tid][0] + s4[tid][1] + s4[tid][2] + s4[tid][3];
    const float q = q4[tid][0] + q4[tid][1] + q4[tid][2] + q4[tid][3];
    const float mu2  = s * (1.f / 320.f);
    const float var2 = q * (1.f / 320.f) - mu2 * mu2;
    const float rs2  = rsqrtf(var2 + LN_EPS);
    rsm[tid][0] = rs2;
    rsm[tid][1] = mu2 * rs2;
  }
  __syncthreads();

  // D: apply LN2 + leaky + per-lane W3-dot partial (overwrites s-partials)
#pragma unroll
  for (int mf = 0; mf < 4; ++mf) {
#pragma unroll
    for (int r = 0; r < 4; ++r) {
      const int rw = mf * 16 + g * 4 + r;
      const float rs2 = rsm[rw][0], murs2 = rsm[rw][1];
      float dsum = 0.f;
#pragma unroll
      for (int nf = 0; nf < 5; ++nf) {
        float v = fmaf(fmaf(acc[mf][nf][r], rs2, -murs2), g2c[nf], be2c[nf]);
        v = fmaxf(v, SLOPE * v);
        dsum = fmaf(v, w3c[nf], dsum);
      }
      scr[rw * 65 + wc * 16 + r16] = dsum;
    }
  }
  __syncthreads();

  // E1: quarter sums
  {
    const int r = tid & 63, qq = tid >> 6;
    float s = 0.f;
#pragma unroll
    for (int k = 0; k < 16; ++k)
      s += scr[r * 65 + qq * 16 + k];
    e4[r][qq] = s;
  }
  __syncthreads();

  // E2: final
  if (tid < 64) {
    const float tot = e4[tid][0] + e4[tid][1] + e4[tid][2] + e4[tid][3] + b3[0];
    out[i * 512 + j0 + tid] = fabsf(tot);
  }
}

// ---------------------------------------------------------------------------
extern "C" void kernel_launch(void* const* d_in, const int* in_sizes, int n_in,
                              void* d_out, int out_size, void* d_ws, size_t ws_size,
                              hipStream_t stream) {
  const float* robot  = (const float*)d_in[0];
  const float* object = (const float*)d_in[1];
  const float* lang   = (const float*)d_in[2];
  const float* W1  = (const float*)d_in[3];
  const float* b1  = (const float*)d_in[4];
  const float* g1  = (const float*)d_in[5];
  const float* be1 = (const float*)d_in[6];
  const float* W2  = (const float*)d_in[7];
  const float* b2  = (const float*)d_in[8];
  const float* g2  = (const float*)d_in[9];
  const float* be2 = (const float*)d_in[10];
  const float* W3  = (const float*)d_in[11];
  const float* b3  = (const float*)d_in[12];
  float* out = (float*)d_out;

  float* U     = (float*)d_ws;            // 512*320 f32
  float* V     = U + 512 * 320;           // 512*320 f32
  float* stats = V + 512 * 320;           // 2048 f32
  __hip_bfloat16* W2F   = (__hip_bfloat16*)(stats + 2048);  // 320*320 bf16
  __hip_bfloat16* Ub    = W2F + 320 * 320;   // 512*320 bf16 (linear)
  __hip_bfloat16* VbF   = Ub + 512 * 320;    // 512*320 bf16 (dot-frag-major)
  __hip_bfloat16* AcatU = VbF + 512 * 320;   // 512*320 bf16
  __hip_bfloat16* AcatV = AcatU + 512 * 320; // 512*320 bf16
  __hip_bfloat16* W1Ft  = AcatV + 512 * 320; // 320*320 bf16 (frag-major)
  __hip_bfloat16* W1Fb  = W1Ft + 320 * 320;  // 320*320 bf16 (frag-major)

  convert_kernel<<<556, 256, 0, stream>>>(robot, object, lang, W1, W2,
                                          AcatU, AcatV, W1Ft, W1Fb, W2F);
  prep_gemm<<<dim3(8, 2), 256, 0, stream>>>(AcatU, AcatV, W1Ft, W1Fb, b1,
                                            U, V, Ub, VbF, stats);
  fused_main<<<dim3(512, 8), 256, 0, stream>>>(U, V, Ub, VbF, W2F, stats,
                                               g1, be1, b2, g2, be2, W3, b3,
                                               out);
}